// Round 21
// baseline (234.760 us; speedup 1.0000x reference)
//
#include <hip/hip_runtime.h>
#include <math.h>

#define MTOT 42000
#define NB 8
#define NCLS 80
#define CAP_LIST 4096
#define NT_MAX 2048
#define GX_MAIN 165                 // ceil(42000/256)
#define NBLK_MAIN (GX_MAIN*NB)      // 1320
#define NCHB 8                      // bestprior chunks per target
#define CSB 5250                    // 42000/8
#define TCH 512                     // match target-staging chunk
#define TST 384                     // ties LDS staging per image

// ---- workspace byte offsets ----
#define O_OVR 0
#define O_GIX (O_OVR + NB*MTOT*4)
#define O_LSC (O_GIX + NB*MTOT*4)
#define O_BCE (O_LSC + NB*MTOT*4)
#define O_LJ  (O_BCE + NB*MTOT*4)
#define O_BPP (((O_LJ + NT_MAX*4 + 7)/8)*8)  // u64 partials [NT_MAX][NCHB]
#define O_HP  (O_BPP + NT_MAX*NCHB*8)    // coarse-hist partials [NBLK_MAIN][256]
#define O_PA  (O_HP + NBLK_MAIN*256*4)   // posloss float4 partials [NBLK_MAIN]
#define O_PN  (O_PA + NBLK_MAIN*16)      // npos int partials [NBLK_MAIN]
#define O_P2  (O_PN + NBLK_MAIN*4)       // select float2 partials [NBLK_MAIN]
#define O_BINL (O_P2 + NBLK_MAIN*8)      // tie list [NB][CAP_LIST][2]
// kernel-zeroed region (zeroed by big0; consumed >=2 dispatches later):
#define O_HB  (((O_BINL + NB*CAP_LIST*2*4 + 255)/256)*256)
#define O_ACCI (O_HB + NB*256*4)         // acci[0..31]
#define O_ZEND (O_ACCI + 128)
#define ZWORDS ((O_ZEND - O_HB)/4)
#define ZBLK ((ZWORDS + 255)/256)
// acci: [0]=num_pos [2..9]=coarse ca [10..17]=kres [18..25]=tie counters

__device__ __forceinline__ float iou_cxcywh(float acx,float acy,float aw,float ah,
                                            float bcx,float bcy,float bw,float bh){
  float ax0=acx-aw*0.5f, ay0=acy-ah*0.5f, ax1=acx+aw*0.5f, ay1=acy+ah*0.5f;
  float bx0=bcx-bw*0.5f, by0=bcy-bh*0.5f, bx1=bcx+bw*0.5f, by1=bcy+bh*0.5f;
  float tlx=fmaxf(ax0,bx0), tly=fmaxf(ay0,by0);
  float brx=fminf(ax1,bx1), bry=fminf(ay1,by1);
  float wx=fmaxf(brx-tlx,0.f), wy=fmaxf(bry-tly,0.f);
  float inter=wx*wy;
  return inter/(aw*ah+bw*bh-inter+1e-9f);
}

__device__ __forceinline__ float sl1(float x){
  float ax=fabsf(x); return ax<1.f ? 0.5f*ax*ax : ax-0.5f;
}

__device__ __forceinline__ void feat_base(const float* f0,const float* f1,const float* f2,
                                          int i,int m,const float** basep,int* hwp){
  const float* fp; int hw, loc;
  if(m<32000){ fp=f0; hw=6400; loc=m; }
  else if(m<40000){ fp=f1; hw=1600; loc=m-32000; }
  else { fp=f2; hw=400; loc=m-40000; }
  int a=loc/hw, p=loc-a*hw;
  *basep = fp + (size_t)(i*425 + a*85)*(size_t)hw + p;
  *hwp = hw;
}

// inline fine-scan: 16-bit boundary bin + residual
__device__ __forceinline__ void fine_scan(const unsigned* hb,int ca,int kres,int* bs_out,int* r_out){
  if(ca==0x7fffffff){ *bs_out=0x7fffffff; *r_out=0; return; }
  int run=0, bs=-1, r=0;
  for(int f=255;f>=0;f--){
    int cb=(int)hb[f];
    if(run<kres && run+cb>=kres){ bs=(ca<<8)|f; r=kres-run; break; }
    run+=cb;
  }
  if(bs<0){ bs=(ca<<8); r=kres-run; }
  *bs_out=bs; *r_out=r;
}

// mega fusion: zero(HB/acci) | lj-prep | match(ballot-compact)+lc | bpA
__global__ void k_big0(const float* __restrict__ f0,const float* __restrict__ f1,const float* __restrict__ f2,
                       const float* __restrict__ tg,const float* __restrict__ priors,
                       int nt,int b0,int b1,
                       int* __restrict__ lj,unsigned* __restrict__ zbase,
                       float* __restrict__ ovr,int* __restrict__ gix,
                       float* __restrict__ lsc,float* __restrict__ bcearr,
                       unsigned* __restrict__ histP,int* __restrict__ partN,
                       unsigned long long* __restrict__ bpp){
  __shared__ float st[TCH*6];
  __shared__ float sc[TCH*4];
  __shared__ int cidx[TCH];
  __shared__ int s_ncomp;
  __shared__ unsigned long long su[256];
  __shared__ unsigned h[256];
  __shared__ int snp[4];
  int b=blockIdx.x, tid=threadIdx.x, lane=tid&63, wid=tid>>6;
  if(b<ZBLK){
    int w=b*256+tid;
    if(w<ZWORDS) zbase[w]=0u;
    return;
  }
  if(b<b0){
    int t=(b-ZBLK)*256+tid;
    if(t>=nt) return;
    int img=(int)tg[t*6];
    int j=0;
    for(int q=0;q<t;q++) if((int)tg[q*6]==img) j++;
    lj[t]=j;
    return;
  }
  if(b<b1){
    // ---- match + lc fused: stage chunk, wave-0 ballot-compact same-image targets ----
    int idx=b-b0;
    int i=idx/GX_MAIN, cb=idx-(idx/GX_MAIN)*GX_MAIN;
    int m=cb*256+tid;
    bool valid=(m<MTOT);
    h[tid]=0u;
    const float* basep=f0; int hw=6400;
    float obj=0.f;
    if(valid){ feat_base(f0,f1,f2,i,m,&basep,&hw); obj=basep[(size_t)4*hw]; }
    float4 pr=make_float4(0.f,0.f,1.f,1.f);
    if(valid) pr=((const float4*)priors)[m];
    float maxv=-1.f; int bi=0;
    for(int base=0;base<nt;base+=TCH){
      int nch=min(TCH,nt-base);
      for(int j=tid;j<nch;j+=256){
        #pragma unroll
        for(int q=0;q<6;q++) st[j*6+q]=tg[(base+j)*6+q];
      }
      __syncthreads();
      if(tid<64){
        int cnt=0;
        for(int bb=0;bb<nch;bb+=64){
          int j=bb+tid;
          bool f=(j<nch)&&((int)st[j*6]==i);
          unsigned long long mk=__ballot(f);
          if(f){
            int pos=cnt+__popcll(mk&((1ull<<tid)-1ull));
            cidx[pos]=base+j;
            sc[pos*4+0]=st[j*6+2]; sc[pos*4+1]=st[j*6+3];
            sc[pos*4+2]=st[j*6+4]; sc[pos*4+3]=st[j*6+5];
          }
          cnt+=__popcll(mk);
        }
        if(tid==0) s_ncomp=cnt;
      }
      __syncthreads();
      int nci=s_ncomp;
      if(valid){
        for(int j=0;j<nci;j++){
          float v=iou_cxcywh(sc[j*4+0],sc[j*4+1],sc[j*4+2],sc[j*4+3],pr.x,pr.y,pr.z,pr.w);
          if(v>maxv){ maxv=v; bi=cidx[j]; }
        }
      }
      __syncthreads();
    }
    int npos=0;
    if(valid){
      int gid=i*MTOT+m;
      ovr[gid]=maxv; gix[gid]=bi;
      int gi=min(max(bi,0),nt-1);
      float tc=tg[gi*6+1]+1.f;
      bool pos=(maxv>=0.5f)&&(tc>0.f);
      float sp=log1pf(expf(-fabsf(obj)));
      float bce=fmaxf(obj,0.f)-(pos?obj:0.f)+sp;
      float lc=pos?0.f:(fmaxf(-obj,0.f)+sp);
      lsc[gid]=lc; bcearr[gid]=bce;
      atomicAdd(&h[__float_as_uint(lc)>>24],1u);
      npos=pos?1:0;
    }
    #pragma unroll
    for(int o=32;o>0;o>>=1) npos+=__shfl_xor(npos,o);
    if(lane==0) snp[wid]=npos;
    __syncthreads();
    histP[(size_t)idx*256+tid]=h[tid];
    if(tid==0) partN[idx]=snp[0]+snp[1]+snp[2]+snp[3];
  } else {
    // ---- bpA: chunked best-prior partials (8 chunks/target) ----
    int idx=b-b1;
    int t=idx/NCHB, c=idx-(idx/NCHB)*NCHB;
    float acx=tg[t*6+2],acy=tg[t*6+3],aw=tg[t*6+4],ah=tg[t*6+5];
    int m0=c*CSB, m1=min(m0+CSB,MTOT);
    float bv=-1.f; int bm=0;
    for(int m=m0+tid;m<m1;m+=256){
      float4 pr=((const float4*)priors)[m];
      float v=iou_cxcywh(acx,acy,aw,ah,pr.x,pr.y,pr.z,pr.w);
      if(v>bv){ bv=v; bm=m; }
    }
    unsigned long long p=(bv<0.f)?0ull
        :(((unsigned long long)__float_as_uint(bv))<<32)|(unsigned)(~bm);
    su[tid]=p;
    __syncthreads();
    for(int o=128;o>0;o>>=1){
      if(tid<o){ if(su[tid+o]>su[tid]) su[tid]=su[tid+o]; }
      __syncthreads();
    }
    if(tid==0) bpp[(size_t)t*NCHB+c]=su[0];
  }
}

// bpB + forced-prior scatter + lc/bce patch + CENTRALIZED np reduce & coarse scan
__global__ void k_bpsc(const float* __restrict__ f0,const float* __restrict__ f1,const float* __restrict__ f2,
                       const float* __restrict__ tg,int nt,
                       const unsigned long long* __restrict__ bpp,
                       const int* __restrict__ lj,
                       float* __restrict__ ovr,const int* __restrict__ gix,
                       float* __restrict__ lsc,float* __restrict__ bcearr,
                       const unsigned* __restrict__ histP,const int* __restrict__ partN,
                       int* __restrict__ acci){
  __shared__ int tbp[NT_MAX];
  __shared__ int timg[NT_MAX];
  __shared__ int hd[NB*256];
  __shared__ int an[256];
  __shared__ int npd;
  int tid=threadIdx.x;
  for(int e=tid;e<NB*256;e+=256) hd[e]=0;
  if(tid==0) npd=0;
  // phase A: bpB
  for(int t=tid;t<nt;t+=256){
    unsigned long long best=0ull;
    const unsigned long long* pp=&bpp[(size_t)t*NCHB];
    #pragma unroll
    for(int c=0;c<NCHB;c++){ unsigned long long v=pp[c]; if(v>best) best=v; }
    int bm=~((unsigned)(best&0xFFFFFFFFull));
    tbp[t]=min(max(bm,0),MTOT-1);
    timg[t]=(int)tg[t*6];
  }
  __syncthreads();
  // phase B: scatter + patch (hist deltas in LDS)
  for(int t=tid;t<nt;t+=256){
    int img=timg[t];
    if(img<0||img>=NB) continue;
    int myp=tbp[t];
    bool last=true;
    for(int q=t+1;q<nt;q++) if(timg[q]==img&&tbp[q]==myp){ last=false; break; }
    if(!last) continue;
    int gid=img*MTOT+myp;
    float ljv=(float)lj[t];
    float ov_old=ovr[gid];
    ovr[gid]=ljv;
    int gi=min(max(gix[gid],0),nt-1);
    float tc=tg[gi*6+1]+1.f;
    bool po=(ov_old>=0.5f)&&(tc>0.f);
    bool pn=(ljv>=0.5f)&&(tc>0.f);
    const float* basep; int hw;
    feat_base(f0,f1,f2,img,myp,&basep,&hw);
    float obj=basep[(size_t)4*hw];
    float sp=log1pf(expf(-fabsf(obj)));
    float bcen=fmaxf(obj,0.f)-(pn?obj:0.f)+sp;
    float lcn=pn?0.f:(fmaxf(-obj,0.f)+sp);
    float lco=lsc[gid];
    lsc[gid]=lcn; bcearr[gid]=bcen;
    atomicAdd(&hd[img*256+(int)(__float_as_uint(lco)>>24)],-1);
    atomicAdd(&hd[img*256+(int)(__float_as_uint(lcn)>>24)], 1);
    atomicAdd(&npd,(pn?1:0)-(po?1:0));
  }
  __syncthreads();
  // phase C: reduce coarse-hist partials into hd (coalesced 1KB rows)
  for(int img=0;img<NB;img++){
    int s=0;
    #pragma unroll 4
    for(int blk=0;blk<GX_MAIN;blk++) s+=(int)histP[(size_t)(img*GX_MAIN+blk)*256+tid];
    hd[img*256+tid]+=s;
  }
  // phase D: np reduce
  int n=0;
  for(int e=tid;e<NBLK_MAIN;e+=256) n+=partN[e];
  an[tid]=n;
  __syncthreads();
  for(int o=128;o>0;o>>=1){ if(tid<o) an[tid]+=an[tid+o]; __syncthreads(); }
  int np=an[0]+npd;
  // phase E: parallel coarse scans (threads 0..7)
  if(tid==0) acci[0]=np;
  if(tid<NB){
    int i=tid;
    int kk=min(np,MTOT-np);
    if(kk<=0){ acci[2+i]=0x7fffffff; acci[10+i]=0; }
    else{
      int run=0, ca=-1, kres=0;
      for(int c2=255;c2>=0;c2--){
        int x=hd[i*256+c2];
        if(run<kk&&run+x>=kk){ ca=c2; kres=kk-run; break; }
        run+=x;
      }
      if(ca<0){ ca=0; kres=kk-run; }
      acci[2+i]=ca; acci[10+i]=kres;
    }
  }
}

// horizontal fusion: [0,1320) fine hist (ca from acci) | [1320,2640) positive losses
__global__ void k_big2(const float* __restrict__ f0,const float* __restrict__ f1,const float* __restrict__ f2,
                       const float* __restrict__ tg,const float* __restrict__ priors,
                       const float* __restrict__ ovr,const int* __restrict__ gix,
                       const float* __restrict__ lsc,const float* __restrict__ bcearr,
                       const int* __restrict__ acci,int nt,
                       unsigned* __restrict__ histB,float4* __restrict__ partA){
  __shared__ unsigned hf[256];
  __shared__ float rA[4],rB[4],rC[4],rD[4];
  int b=blockIdx.x, tid=threadIdx.x, lane=tid&63, wid=tid>>6;
  if(b<NBLK_MAIN){
    int i=b/GX_MAIN, cb=b-(b/GX_MAIN)*GX_MAIN;
    int ca=acci[2+i];
    hf[tid]=0u;
    __syncthreads();
    int m=cb*256+tid;
    if(m<MTOT && ca!=0x7fffffff){
      unsigned u=__float_as_uint(lsc[i*MTOT+m]);
      if((int)(u>>24)==ca) atomicAdd(&hf[(u>>16)&0xFF],1u);
    }
    __syncthreads();
    unsigned c=hf[tid];
    if(c) atomicAdd(&histB[i*256+tid],c);
  } else {
    int idx=b-NBLK_MAIN;
    int i=idx/GX_MAIN, cb=idx-(idx/GX_MAIN)*GX_MAIN;
    int m=cb*256+tid;
    bool valid=(m<MTOT);
    float lxy=0.f,lwh=0.f,bcep=0.f,wce=0.f;
    bool pos=false; int gi=0;
    if(valid){
      int gid=i*MTOT+m;
      float ov=ovr[gid];
      gi=min(max(gix[gid],0),nt-1);
      float tc=tg[gi*6+1]+1.f;
      pos=(ov>=0.5f)&&(tc>0.f);
      if(pos){
        const float* base; int hw;
        feat_base(f0,f1,f2,i,m,&base,&hw);
        bcep=bcearr[gid];
        float4 pr=((const float4*)priors)[m];
        float bx=tg[gi*6+2],by=tg[gi*6+3],bw=tg[gi*6+4],bh=tg[gi*6+5];
        float tx=(bx-pr.x)/pr.z, ty=(by-pr.y)/pr.w;
        float tw=logf(bw/pr.z), th=logf(bh/pr.w);
        lxy=sl1(base[0]-tx)+sl1(base[(size_t)hw]-ty);
        lwh=sl1(base[(size_t)2*hw]-tw)+sl1(base[(size_t)3*hw]-th);
      }
    }
    unsigned long long mask=__ballot(valid&&pos);
    while(mask){
      int s=__ffsll(mask)-1;
      mask&=mask-1;
      int m_s=__shfl(m,s);
      int gi_s=__shfl(gi,s);
      const float* bs2; int hws;
      feat_base(f0,f1,f2,i,m_s,&bs2,&hws);
      int label=(int)(tg[gi_s*6+1]+1.f)-1;
      label=min(NCLS-1,max(0,label));
      float v0=bs2[(size_t)(5+lane)*hws];
      float v1=(lane<16)?bs2[(size_t)(69+lane)*hws]:-3.0e38f;
      float mx=fmaxf(v0,v1);
      #pragma unroll
      for(int o=32;o>0;o>>=1) mx=fmaxf(mx,__shfl_xor(mx,o));
      float se=expf(v0-mx)+((lane<16)?expf(v1-mx):0.f);
      float xl=((lane==label)?v0:0.f)+((lane<16&&lane+64==label)?v1:0.f);
      #pragma unroll
      for(int o=32;o>0;o>>=1){ se+=__shfl_xor(se,o); xl+=__shfl_xor(xl,o); }
      wce+=logf(se)+mx-xl;
    }
    #pragma unroll
    for(int o=32;o>0;o>>=1){
      lxy+=__shfl_xor(lxy,o); lwh+=__shfl_xor(lwh,o); bcep+=__shfl_xor(bcep,o);
    }
    if(lane==0){ rA[wid]=lxy; rB[wid]=lwh; rC[wid]=wce; rD[wid]=bcep; }
    __syncthreads();
    if(tid==0)
      partA[idx]=make_float4(rA[0]+rA[1]+rA[2]+rA[3], rB[0]+rB[1]+rB[2]+rB[3],
                             rC[0]+rC[1]+rC[2]+rC[3], rD[0]+rD[1]+rD[2]+rD[3]);
  }
}

// select negatives above 16-bit threshold (fine_scan locally); partials + tie list
__global__ void k_select(const float* __restrict__ lsc,const float* __restrict__ bcearr,
                         const unsigned* __restrict__ histB,
                         int* __restrict__ acci,float2* __restrict__ part2,
                         int* __restrict__ binlist){
  __shared__ unsigned hb[256];
  __shared__ int sbs;
  __shared__ float ss[4]; __shared__ float sc2[4];
  int tid=threadIdx.x, lane=tid&63, wid=tid>>6;
  int i=blockIdx.y;
  int ca=acci[2+i], kres=acci[10+i];
  hb[tid]=(ca==0x7fffffff)?0u:histB[i*256+tid];
  __syncthreads();
  if(tid==0){ int bs,r; fine_scan(hb,ca,kres,&bs,&r); sbs=bs; }
  __syncthreads();
  int bs_=sbs;
  int m=blockIdx.x*256+tid;
  float s=0.f, c=0.f;
  if(m<MTOT){
    int gid=i*MTOT+m;
    unsigned u=__float_as_uint(lsc[gid]);
    int bin=(int)(u>>16);
    if(bin>bs_){ s=bcearr[gid]; c=1.f; }
    else if(bin==bs_){
      int idx=atomicAdd(&acci[18+i],1);
      if(idx<CAP_LIST){
        binlist[((size_t)i*CAP_LIST+idx)*2  ]=(int)u;
        binlist[((size_t)i*CAP_LIST+idx)*2+1]=gid;
      }
    }
  }
  #pragma unroll
  for(int o=32;o>0;o>>=1){ s+=__shfl_xor(s,o); c+=__shfl_xor(c,o); }
  if(lane==0){ ss[wid]=s; sc2[wid]=c; }
  __syncthreads();
  if(tid==0) part2[blockIdx.y*gridDim.x+blockIdx.x]=make_float2(ss[0]+ss[1]+ss[2]+ss[3], sc2[0]+sc2[1]+sc2[2]+sc2[3]);
}

// ties (wave w = image w, parallel latency chains) + final combine; 1 block x 512
__global__ void k_tiesfinal(const float* __restrict__ bcearr,const unsigned* __restrict__ histB,
                            int* __restrict__ acci,const int* __restrict__ binlist,
                            const float4* __restrict__ partA,const float2* __restrict__ part2,
                            float* __restrict__ out){
  __shared__ unsigned hb[NB*256];
  __shared__ int sbs[NB], sr2[NB];
  __shared__ int stg[NB*TST*2];
  __shared__ float tsumW[NB]; __shared__ float tcntW[NB];
  __shared__ float a0[512],a1[512],a2[512],a3[512],s0[512],s1[512];
  int tid=threadIdx.x, w=tid>>6, lane=tid&63;
  int ca=acci[2+w], kres=acci[10+w];
  for(int e=lane;e<256;e+=64) hb[w*256+e]=(ca==0x7fffffff)?0u:histB[w*256+e];
  __syncthreads();
  if(lane==0){ int bs,r; fine_scan(&hb[w*256],ca,kres,&bs,&r); sbs[w]=bs; sr2[w]=r; }
  __syncthreads();
  int bs=sbs[w], r=sr2[w];
  int n=min(acci[18+w],CAP_LIST);
  int nst=min(n,TST);
  if(bs!=0x7fffffff){
    for(int e=lane;e<nst;e+=64){
      stg[(w*TST+e)*2  ]=binlist[((size_t)w*CAP_LIST+e)*2  ];
      stg[(w*TST+e)*2+1]=binlist[((size_t)w*CAP_LIST+e)*2+1];
    }
  }
  __syncthreads();
  float tsum=0.f, tcnt=0.f;
  if(bs!=0x7fffffff){
    for(int e=lane;e<n;e+=64){
      unsigned ue; int ge;
      if(e<nst){ ue=(unsigned)stg[(w*TST+e)*2]; ge=stg[(w*TST+e)*2+1]; }
      else{ ue=(unsigned)binlist[((size_t)w*CAP_LIST+e)*2]; ge=binlist[((size_t)w*CAP_LIST+e)*2+1]; }
      int rank=0;
      for(int q=0;q<n;q++){
        unsigned uq; int gq;
        if(q<nst){ uq=(unsigned)stg[(w*TST+q)*2]; gq=stg[(w*TST+q)*2+1]; }
        else{ uq=(unsigned)binlist[((size_t)w*CAP_LIST+q)*2]; gq=binlist[((size_t)w*CAP_LIST+q)*2+1]; }
        rank += ((uq>ue)||(uq==ue&&gq<ge))?1:0;
      }
      if(rank<r){ tsum+=bcearr[ge]; tcnt+=1.f; }
    }
  }
  #pragma unroll
  for(int o=32;o>0;o>>=1){ tsum+=__shfl_xor(tsum,o); tcnt+=__shfl_xor(tcnt,o); }
  if(lane==0){ tsumW[w]=tsum; tcntW[w]=tcnt; }
  __syncthreads();
  float x=0,y=0,z=0,ww=0,ns=0,nc=0;
  for(int e=tid;e<NBLK_MAIN;e+=512){
    float4 p=partA[e]; x+=p.x; y+=p.y; z+=p.z; ww+=p.w;
    float2 q=part2[e]; ns+=q.x; nc+=q.y;
  }
  a0[tid]=x; a1[tid]=y; a2[tid]=z; a3[tid]=ww; s0[tid]=ns; s1[tid]=nc;
  __syncthreads();
  for(int o=256;o>0;o>>=1){
    if(tid<o){
      a0[tid]+=a0[tid+o]; a1[tid]+=a1[tid+o]; a2[tid]+=a2[tid+o]; a3[tid]+=a3[tid+o];
      s0[tid]+=s0[tid+o]; s1[tid]+=s1[tid+o];
    }
    __syncthreads();
  }
  if(tid==0){
    float negsum=s0[0], negcnt=s1[0];
    for(int im=0;im<NB;im++){ negsum+=tsumW[im]; negcnt+=tcntW[im]; }
    int np=acci[0];
    float npf=(float)np;
    float den2=fmaxf(2.f*npf,1.f);
    float lbox=a0[0]/den2+a1[0]/den2;
    float lcls=a2[0]/fmaxf(npf,1.f);
    float selc=npf+negcnt;
    float lobj=(a3[0]+negsum)/fmaxf(selc,1.f);
    out[0]=lbox+lcls+lobj;
    out[1]=lbox;
    out[2]=lobj;
    out[3]=lcls;
  }
}

extern "C" void kernel_launch(void* const* d_in, const int* in_sizes, int n_in,
                              void* d_out, int out_size, void* d_ws, size_t ws_size,
                              hipStream_t stream) {
  const float* f0=(const float*)d_in[0];
  const float* f1=(const float*)d_in[1];
  const float* f2=(const float*)d_in[2];
  const float* tg=(const float*)d_in[3];
  const float* priors=(const float*)d_in[4];
  int nt = in_sizes[3]/6;
  if(nt>NT_MAX) nt=NT_MAX;
  if(nt<1) nt=1;

  char* ws=(char*)d_ws;
  float*    ovr    =(float*)   (ws+O_OVR);
  int*      gix    =(int*)     (ws+O_GIX);
  float*    lsc    =(float*)   (ws+O_LSC);
  float*    bcearr =(float*)   (ws+O_BCE);
  int*      lj     =(int*)     (ws+O_LJ);
  unsigned long long* bpp=(unsigned long long*)(ws+O_BPP);
  unsigned* histP  =(unsigned*)(ws+O_HP);
  float4*   partA  =(float4*)  (ws+O_PA);
  int*      partN  =(int*)     (ws+O_PN);
  float2*   part2  =(float2*)  (ws+O_P2);
  int*      binlist=(int*)     (ws+O_BINL);
  unsigned* histB  =(unsigned*)(ws+O_HB);
  int*      acci   =(int*)     (ws+O_ACCI);
  unsigned* zbase  =(unsigned*)(ws+O_HB);

  int ntb=(nt+255)/256;
  int b0=ZBLK+ntb, b1=b0+NBLK_MAIN;
  k_big0<<<b1+nt*NCHB,256,0,stream>>>(f0,f1,f2,tg,priors,nt,b0,b1,lj,zbase,ovr,gix,lsc,bcearr,histP,partN,bpp);
  k_bpsc<<<1,256,0,stream>>>(f0,f1,f2,tg,nt,bpp,lj,ovr,gix,lsc,bcearr,histP,partN,acci);
  k_big2<<<2*NBLK_MAIN,256,0,stream>>>(f0,f1,f2,tg,priors,ovr,gix,lsc,bcearr,acci,nt,histB,partA);
  dim3 gm(GX_MAIN, NB);
  k_select<<<gm,256,0,stream>>>(lsc,bcearr,histB,acci,part2,binlist);
  k_tiesfinal<<<1,512,0,stream>>>(bcearr,histB,acci,binlist,partA,part2,(float*)d_out);
}

// Round 24
// 153.538 us; speedup vs baseline: 1.5290x; 1.5290x over previous
//
#include <hip/hip_runtime.h>
#include <math.h>

#define MTOT 42000
#define NB 8
#define NCLS 80
#define CAP_LIST 4096
#define NT_MAX 2048
#define GX_MAIN 165                 // ceil(42000/256)
#define NBLK_MAIN (GX_MAIN*NB)      // 1320
#define NCHB 8                      // bestprior chunks per target
#define CSB 5250                    // 42000/8
#define TCH 512                     // match target-staging chunk
#define TST 384                     // ties LDS staging per image

// ---- workspace byte offsets ----
#define O_OVR 0
#define O_GIX (O_OVR + NB*MTOT*4)
#define O_LSC (O_GIX + NB*MTOT*4)
#define O_BCE (O_LSC + NB*MTOT*4)
#define O_LJ  (O_BCE + NB*MTOT*4)
#define O_BPP (((O_LJ + NT_MAX*4 + 7)/8)*8)  // u64 partials [NT_MAX][NCHB]
#define O_HP  (O_BPP + NT_MAX*NCHB*8)    // coarse-hist partials [NBLK_MAIN][256]
#define O_HD  (O_HP + NBLK_MAIN*256*4)   // coarse-hist deltas [NB][256] int (written by bpsc)
#define O_PA  (O_HD + NB*256*4)          // posloss float4 partials [NBLK_MAIN]
#define O_PN  (O_PA + NBLK_MAIN*16)      // npos int partials [NBLK_MAIN]
#define O_P2  (O_PN + NBLK_MAIN*4)       // select float2 partials [NBLK_MAIN]
#define O_BINL (O_P2 + NBLK_MAIN*8)      // tie list [NB][CAP_LIST][2]
// kernel-zeroed region (zeroed by big0; consumed >=2 dispatches later):
#define O_HB  (((O_BINL + NB*CAP_LIST*2*4 + 255)/256)*256)
#define O_ACCI (O_HB + NB*256*4)         // acci[0..31]
#define O_ZEND (O_ACCI + 128)
#define ZWORDS ((O_ZEND - O_HB)/4)
#define ZBLK ((ZWORDS + 255)/256)
// acci: [0]=num_pos [2..9]=coarse ca [10..17]=kres [18..25]=tie counters [26]=npDelta

__device__ __forceinline__ float iou_cxcywh(float acx,float acy,float aw,float ah,
                                            float bcx,float bcy,float bw,float bh){
  float ax0=acx-aw*0.5f, ay0=acy-ah*0.5f, ax1=acx+aw*0.5f, ay1=acy+ah*0.5f;
  float bx0=bcx-bw*0.5f, by0=bcy-bh*0.5f, bx1=bcx+bw*0.5f, by1=bcy+bh*0.5f;
  float tlx=fmaxf(ax0,bx0), tly=fmaxf(ay0,by0);
  float brx=fminf(ax1,bx1), bry=fminf(ay1,by1);
  float wx=fmaxf(brx-tlx,0.f), wy=fmaxf(bry-tly,0.f);
  float inter=wx*wy;
  return inter/(aw*ah+bw*bh-inter+1e-9f);
}

__device__ __forceinline__ float sl1(float x){
  float ax=fabsf(x); return ax<1.f ? 0.5f*ax*ax : ax-0.5f;
}

__device__ __forceinline__ void feat_base(const float* f0,const float* f1,const float* f2,
                                          int i,int m,const float** basep,int* hwp){
  const float* fp; int hw, loc;
  if(m<32000){ fp=f0; hw=6400; loc=m; }
  else if(m<40000){ fp=f1; hw=1600; loc=m-32000; }
  else { fp=f2; hw=400; loc=m-40000; }
  int a=loc/hw, p=loc-a*hw;
  *basep = fp + (size_t)(i*425 + a*85)*(size_t)hw + p;
  *hwp = hw;
}

// inline fine-scan: 16-bit boundary bin + residual
__device__ __forceinline__ void fine_scan(const unsigned* hb,int ca,int kres,int* bs_out,int* r_out){
  if(ca==0x7fffffff){ *bs_out=0x7fffffff; *r_out=0; return; }
  int run=0, bs=-1, r=0;
  for(int f=255;f>=0;f--){
    int cb=(int)hb[f];
    if(run<kres && run+cb>=kres){ bs=(ca<<8)|f; r=kres-run; break; }
    run+=cb;
  }
  if(bs<0){ bs=(ca<<8); r=kres-run; }
  *bs_out=bs; *r_out=r;
}

// mega fusion: zero(HB/acci) | lj-prep | match(ballot-compact)+lc | bpA
__global__ void k_big0(const float* __restrict__ f0,const float* __restrict__ f1,const float* __restrict__ f2,
                       const float* __restrict__ tg,const float* __restrict__ priors,
                       int nt,int b0,int b1,
                       int* __restrict__ lj,unsigned* __restrict__ zbase,
                       float* __restrict__ ovr,int* __restrict__ gix,
                       float* __restrict__ lsc,float* __restrict__ bcearr,
                       unsigned* __restrict__ histP,int* __restrict__ partN,
                       unsigned long long* __restrict__ bpp){
  __shared__ float st[TCH*6];
  __shared__ float sc[TCH*4];
  __shared__ int cidx[TCH];
  __shared__ int s_ncomp;
  __shared__ unsigned long long su[256];
  __shared__ unsigned h[256];
  __shared__ int snp[4];
  int b=blockIdx.x, tid=threadIdx.x, lane=tid&63, wid=tid>>6;
  if(b<ZBLK){
    int w=b*256+tid;
    if(w<ZWORDS) zbase[w]=0u;
    return;
  }
  if(b<b0){
    int t=(b-ZBLK)*256+tid;
    if(t>=nt) return;
    int img=(int)tg[t*6];
    int j=0;
    for(int q=0;q<t;q++) if((int)tg[q*6]==img) j++;
    lj[t]=j;
    return;
  }
  if(b<b1){
    // ---- match + lc fused: stage chunk, wave-0 ballot-compact same-image targets ----
    int idx=b-b0;
    int i=idx/GX_MAIN, cb=idx-(idx/GX_MAIN)*GX_MAIN;
    int m=cb*256+tid;
    bool valid=(m<MTOT);
    h[tid]=0u;
    const float* basep=f0; int hw=6400;
    float obj=0.f;
    if(valid){ feat_base(f0,f1,f2,i,m,&basep,&hw); obj=basep[(size_t)4*hw]; }
    float4 pr=make_float4(0.f,0.f,1.f,1.f);
    if(valid) pr=((const float4*)priors)[m];
    float maxv=-1.f; int bi=0;
    for(int base=0;base<nt;base+=TCH){
      int nch=min(TCH,nt-base);
      for(int j=tid;j<nch;j+=256){
        #pragma unroll
        for(int q=0;q<6;q++) st[j*6+q]=tg[(base+j)*6+q];
      }
      __syncthreads();
      if(tid<64){
        int cnt=0;
        for(int bb=0;bb<nch;bb+=64){
          int j=bb+tid;
          bool f=(j<nch)&&((int)st[j*6]==i);
          unsigned long long mk=__ballot(f);
          if(f){
            int pos=cnt+__popcll(mk&((1ull<<tid)-1ull));
            cidx[pos]=base+j;
            sc[pos*4+0]=st[j*6+2]; sc[pos*4+1]=st[j*6+3];
            sc[pos*4+2]=st[j*6+4]; sc[pos*4+3]=st[j*6+5];
          }
          cnt+=__popcll(mk);
        }
        if(tid==0) s_ncomp=cnt;
      }
      __syncthreads();
      int nci=s_ncomp;
      if(valid){
        for(int j=0;j<nci;j++){
          float v=iou_cxcywh(sc[j*4+0],sc[j*4+1],sc[j*4+2],sc[j*4+3],pr.x,pr.y,pr.z,pr.w);
          if(v>maxv){ maxv=v; bi=cidx[j]; }
        }
      }
      __syncthreads();
    }
    int npos=0;
    if(valid){
      int gid=i*MTOT+m;
      ovr[gid]=maxv; gix[gid]=bi;
      int gi=min(max(bi,0),nt-1);
      float tc=tg[gi*6+1]+1.f;
      bool pos=(maxv>=0.5f)&&(tc>0.f);
      float sp=log1pf(expf(-fabsf(obj)));
      float bce=fmaxf(obj,0.f)-(pos?obj:0.f)+sp;
      float lc=pos?0.f:(fmaxf(-obj,0.f)+sp);
      lsc[gid]=lc; bcearr[gid]=bce;
      atomicAdd(&h[__float_as_uint(lc)>>24],1u);
      npos=pos?1:0;
    }
    #pragma unroll
    for(int o=32;o>0;o>>=1) npos+=__shfl_xor(npos,o);
    if(lane==0) snp[wid]=npos;
    __syncthreads();
    histP[(size_t)idx*256+tid]=h[tid];
    if(tid==0) partN[idx]=snp[0]+snp[1]+snp[2]+snp[3];
  } else {
    // ---- bpA: chunked best-prior partials (8 chunks/target) ----
    int idx=b-b1;
    int t=idx/NCHB, c=idx-(idx/NCHB)*NCHB;
    float acx=tg[t*6+2],acy=tg[t*6+3],aw=tg[t*6+4],ah=tg[t*6+5];
    int m0=c*CSB, m1=min(m0+CSB,MTOT);
    float bv=-1.f; int bm=0;
    for(int m=m0+tid;m<m1;m+=256){
      float4 pr=((const float4*)priors)[m];
      float v=iou_cxcywh(acx,acy,aw,ah,pr.x,pr.y,pr.z,pr.w);
      if(v>bv){ bv=v; bm=m; }
    }
    unsigned long long p=(bv<0.f)?0ull
        :(((unsigned long long)__float_as_uint(bv))<<32)|(unsigned)(~bm);
    su[tid]=p;
    __syncthreads();
    for(int o=128;o>0;o>>=1){
      if(tid<o){ if(su[tid+o]>su[tid]) su[tid]=su[tid+o]; }
      __syncthreads();
    }
    if(tid==0) bpp[(size_t)t*NCHB+c]=su[0];
  }
}

// bpB + forced-prior scatter + lc/bce patch (R18-proven); deltas -> histD/acci[26]
__global__ void k_bpsc(const float* __restrict__ f0,const float* __restrict__ f1,const float* __restrict__ f2,
                       const float* __restrict__ tg,int nt,
                       const unsigned long long* __restrict__ bpp,
                       const int* __restrict__ lj,
                       float* __restrict__ ovr,const int* __restrict__ gix,
                       float* __restrict__ lsc,float* __restrict__ bcearr,
                       int* __restrict__ histD,int* __restrict__ acci){
  __shared__ int tbp[NT_MAX];
  __shared__ int timg[NT_MAX];
  __shared__ int hd[NB*256];
  __shared__ int npd;
  int tid=threadIdx.x;
  for(int e=tid;e<NB*256;e+=256) hd[e]=0;
  if(tid==0) npd=0;
  for(int t=tid;t<nt;t+=256){
    unsigned long long best=0ull;
    const unsigned long long* pp=&bpp[(size_t)t*NCHB];
    #pragma unroll
    for(int c=0;c<NCHB;c++){ unsigned long long v=pp[c]; if(v>best) best=v; }
    int bm=~((unsigned)(best&0xFFFFFFFFull));
    tbp[t]=min(max(bm,0),MTOT-1);
    timg[t]=(int)tg[t*6];
  }
  __syncthreads();
  for(int t=tid;t<nt;t+=256){
    int img=timg[t];
    if(img<0||img>=NB) continue;
    int myp=tbp[t];
    bool last=true;
    for(int q=t+1;q<nt;q++) if(timg[q]==img&&tbp[q]==myp){ last=false; break; }
    if(!last) continue;
    int gid=img*MTOT+myp;
    float ljv=(float)lj[t];
    float ov_old=ovr[gid];
    ovr[gid]=ljv;
    int gi=min(max(gix[gid],0),nt-1);
    float tc=tg[gi*6+1]+1.f;
    bool po=(ov_old>=0.5f)&&(tc>0.f);
    bool pn=(ljv>=0.5f)&&(tc>0.f);
    const float* basep; int hw;
    feat_base(f0,f1,f2,img,myp,&basep,&hw);
    float obj=basep[(size_t)4*hw];
    float sp=log1pf(expf(-fabsf(obj)));
    float bcen=fmaxf(obj,0.f)-(pn?obj:0.f)+sp;
    float lcn=pn?0.f:(fmaxf(-obj,0.f)+sp);
    float lco=lsc[gid];
    lsc[gid]=lcn; bcearr[gid]=bcen;
    atomicAdd(&hd[img*256+(int)(__float_as_uint(lco)>>24)],-1);
    atomicAdd(&hd[img*256+(int)(__float_as_uint(lcn)>>24)], 1);
    atomicAdd(&npd,(pn?1:0)-(po?1:0));
  }
  __syncthreads();
  for(int e=tid;e<NB*256;e+=256) histD[e]=hd[e];
  if(tid==0) acci[26]=npd;
}

// centralized np reduce + coarse scan, PARALLEL across images (8 blocks; R13-proven shape)
__global__ void k_redscanA(const unsigned* __restrict__ histP,const int* __restrict__ histD,
                           const int* __restrict__ partN,int* __restrict__ acci){
  __shared__ int hc[256];
  __shared__ int an[256];
  int tid=threadIdx.x, i=blockIdx.x;
  // sum this image's 165 coarse-hist partial rows (coalesced) + delta
  int s=histD[i*256+tid];
  #pragma unroll 4
  for(int blk=0;blk<GX_MAIN;blk++) s+=(int)histP[(size_t)(i*GX_MAIN+blk)*256+tid];
  hc[tid]=s;
  // np reduce (each block redundantly; 1320 ints, L2-hot)
  int n=0;
  for(int e=tid;e<NBLK_MAIN;e+=256) n+=partN[e];
  an[tid]=n;
  __syncthreads();
  for(int o=128;o>0;o>>=1){ if(tid<o) an[tid]+=an[tid+o]; __syncthreads(); }
  int np=an[0]+acci[26];
  if(i==0&&tid==0) acci[0]=np;
  if(tid==0){
    int kk=min(np,MTOT-np);
    if(kk<=0){ acci[2+i]=0x7fffffff; acci[10+i]=0; }
    else{
      int run=0, ca=-1, kres=0;
      for(int c2=255;c2>=0;c2--){
        int x=hc[c2];
        if(run<kk&&run+x>=kk){ ca=c2; kres=kk-run; break; }
        run+=x;
      }
      if(ca<0){ ca=0; kres=kk-run; }
      acci[2+i]=ca; acci[10+i]=kres;
    }
  }
}

// horizontal fusion: [0,1320) fine hist (ca from acci) | [1320,2640) positive losses
__global__ void k_big2(const float* __restrict__ f0,const float* __restrict__ f1,const float* __restrict__ f2,
                       const float* __restrict__ tg,const float* __restrict__ priors,
                       const float* __restrict__ ovr,const int* __restrict__ gix,
                       const float* __restrict__ lsc,const float* __restrict__ bcearr,
                       const int* __restrict__ acci,int nt,
                       unsigned* __restrict__ histB,float4* __restrict__ partA){
  __shared__ unsigned hf[256];
  __shared__ float rA[4],rB[4],rC[4],rD[4];
  int b=blockIdx.x, tid=threadIdx.x, lane=tid&63, wid=tid>>6;
  if(b<NBLK_MAIN){
    int i=b/GX_MAIN, cb=b-(b/GX_MAIN)*GX_MAIN;
    int ca=acci[2+i];
    hf[tid]=0u;
    __syncthreads();
    int m=cb*256+tid;
    if(m<MTOT && ca!=0x7fffffff){
      unsigned u=__float_as_uint(lsc[i*MTOT+m]);
      if((int)(u>>24)==ca) atomicAdd(&hf[(u>>16)&0xFF],1u);
    }
    __syncthreads();
    unsigned c=hf[tid];
    if(c) atomicAdd(&histB[i*256+tid],c);
  } else {
    int idx=b-NBLK_MAIN;
    int i=idx/GX_MAIN, cb=idx-(idx/GX_MAIN)*GX_MAIN;
    int m=cb*256+tid;
    bool valid=(m<MTOT);
    float lxy=0.f,lwh=0.f,bcep=0.f,wce=0.f;
    bool pos=false; int gi=0;
    if(valid){
      int gid=i*MTOT+m;
      float ov=ovr[gid];
      gi=min(max(gix[gid],0),nt-1);
      float tc=tg[gi*6+1]+1.f;
      pos=(ov>=0.5f)&&(tc>0.f);
      if(pos){
        const float* base; int hw;
        feat_base(f0,f1,f2,i,m,&base,&hw);
        bcep=bcearr[gid];
        float4 pr=((const float4*)priors)[m];
        float bx=tg[gi*6+2],by=tg[gi*6+3],bw=tg[gi*6+4],bh=tg[gi*6+5];
        float tx=(bx-pr.x)/pr.z, ty=(by-pr.y)/pr.w;
        float tw=logf(bw/pr.z), th=logf(bh/pr.w);
        lxy=sl1(base[0]-tx)+sl1(base[(size_t)hw]-ty);
        lwh=sl1(base[(size_t)2*hw]-tw)+sl1(base[(size_t)3*hw]-th);
      }
    }
    unsigned long long mask=__ballot(valid&&pos);
    while(mask){
      int s=__ffsll(mask)-1;
      mask&=mask-1;
      int m_s=__shfl(m,s);
      int gi_s=__shfl(gi,s);
      const float* bs2; int hws;
      feat_base(f0,f1,f2,i,m_s,&bs2,&hws);
      int label=(int)(tg[gi_s*6+1]+1.f)-1;
      label=min(NCLS-1,max(0,label));
      float v0=bs2[(size_t)(5+lane)*hws];
      float v1=(lane<16)?bs2[(size_t)(69+lane)*hws]:-3.0e38f;
      float mx=fmaxf(v0,v1);
      #pragma unroll
      for(int o=32;o>0;o>>=1) mx=fmaxf(mx,__shfl_xor(mx,o));
      float se=expf(v0-mx)+((lane<16)?expf(v1-mx):0.f);
      float xl=((lane==label)?v0:0.f)+((lane<16&&lane+64==label)?v1:0.f);
      #pragma unroll
      for(int o=32;o>0;o>>=1){ se+=__shfl_xor(se,o); xl+=__shfl_xor(xl,o); }
      wce+=logf(se)+mx-xl;
    }
    #pragma unroll
    for(int o=32;o>0;o>>=1){
      lxy+=__shfl_xor(lxy,o); lwh+=__shfl_xor(lwh,o); bcep+=__shfl_xor(bcep,o);
    }
    if(lane==0){ rA[wid]=lxy; rB[wid]=lwh; rC[wid]=wce; rD[wid]=bcep; }
    __syncthreads();
    if(tid==0)
      partA[idx]=make_float4(rA[0]+rA[1]+rA[2]+rA[3], rB[0]+rB[1]+rB[2]+rB[3],
                             rC[0]+rC[1]+rC[2]+rC[3], rD[0]+rD[1]+rD[2]+rD[3]);
  }
}

// select negatives above 16-bit threshold (fine_scan locally); partials + tie list
__global__ void k_select(const float* __restrict__ lsc,const float* __restrict__ bcearr,
                         const unsigned* __restrict__ histB,
                         int* __restrict__ acci,float2* __restrict__ part2,
                         int* __restrict__ binlist){
  __shared__ unsigned hb[256];
  __shared__ int sbs;
  __shared__ float ss[4]; __shared__ float sc2[4];
  int tid=threadIdx.x, lane=tid&63, wid=tid>>6;
  int i=blockIdx.y;
  int ca=acci[2+i], kres=acci[10+i];
  hb[tid]=(ca==0x7fffffff)?0u:histB[i*256+tid];
  __syncthreads();
  if(tid==0){ int bs,r; fine_scan(hb,ca,kres,&bs,&r); sbs=bs; }
  __syncthreads();
  int bs_=sbs;
  int m=blockIdx.x*256+tid;
  float s=0.f, c=0.f;
  if(m<MTOT){
    int gid=i*MTOT+m;
    unsigned u=__float_as_uint(lsc[gid]);
    int bin=(int)(u>>16);
    if(bin>bs_){ s=bcearr[gid]; c=1.f; }
    else if(bin==bs_){
      int idx=atomicAdd(&acci[18+i],1);
      if(idx<CAP_LIST){
        binlist[((size_t)i*CAP_LIST+idx)*2  ]=(int)u;
        binlist[((size_t)i*CAP_LIST+idx)*2+1]=gid;
      }
    }
  }
  #pragma unroll
  for(int o=32;o>0;o>>=1){ s+=__shfl_xor(s,o); c+=__shfl_xor(c,o); }
  if(lane==0){ ss[wid]=s; sc2[wid]=c; }
  __syncthreads();
  if(tid==0) part2[blockIdx.y*gridDim.x+blockIdx.x]=make_float2(ss[0]+ss[1]+ss[2]+ss[3], sc2[0]+sc2[1]+sc2[2]+sc2[3]);
}

// ties (wave w = image w, parallel latency chains) + final combine; 1 block x 512
__global__ void k_tiesfinal(const float* __restrict__ bcearr,const unsigned* __restrict__ histB,
                            int* __restrict__ acci,const int* __restrict__ binlist,
                            const float4* __restrict__ partA,const float2* __restrict__ part2,
                            float* __restrict__ out){
  __shared__ unsigned hb[NB*256];
  __shared__ int sbs[NB], sr2[NB];
  __shared__ int stg[NB*TST*2];
  __shared__ float tsumW[NB]; __shared__ float tcntW[NB];
  __shared__ float a0[512],a1[512],a2[512],a3[512],s0[512],s1[512];
  int tid=threadIdx.x, w=tid>>6, lane=tid&63;
  int ca=acci[2+w], kres=acci[10+w];
  for(int e=lane;e<256;e+=64) hb[w*256+e]=(ca==0x7fffffff)?0u:histB[w*256+e];
  __syncthreads();
  if(lane==0){ int bs,r; fine_scan(&hb[w*256],ca,kres,&bs,&r); sbs[w]=bs; sr2[w]=r; }
  __syncthreads();
  int bs=sbs[w], r=sr2[w];
  int n=min(acci[18+w],CAP_LIST);
  int nst=min(n,TST);
  if(bs!=0x7fffffff){
    for(int e=lane;e<nst;e+=64){
      stg[(w*TST+e)*2  ]=binlist[((size_t)w*CAP_LIST+e)*2  ];
      stg[(w*TST+e)*2+1]=binlist[((size_t)w*CAP_LIST+e)*2+1];
    }
  }
  __syncthreads();
  float tsum=0.f, tcnt=0.f;
  if(bs!=0x7fffffff){
    for(int e=lane;e<n;e+=64){
      unsigned ue; int ge;
      if(e<nst){ ue=(unsigned)stg[(w*TST+e)*2]; ge=stg[(w*TST+e)*2+1]; }
      else{ ue=(unsigned)binlist[((size_t)w*CAP_LIST+e)*2]; ge=binlist[((size_t)w*CAP_LIST+e)*2+1]; }
      int rank=0;
      for(int q=0;q<n;q++){
        unsigned uq; int gq;
        if(q<nst){ uq=(unsigned)stg[(w*TST+q)*2]; gq=stg[(w*TST+q)*2+1]; }
        else{ uq=(unsigned)binlist[((size_t)w*CAP_LIST+q)*2]; gq=binlist[((size_t)w*CAP_LIST+q)*2+1]; }
        rank += ((uq>ue)||(uq==ue&&gq<ge))?1:0;
      }
      if(rank<r){ tsum+=bcearr[ge]; tcnt+=1.f; }
    }
  }
  #pragma unroll
  for(int o=32;o>0;o>>=1){ tsum+=__shfl_xor(tsum,o); tcnt+=__shfl_xor(tcnt,o); }
  if(lane==0){ tsumW[w]=tsum; tcntW[w]=tcnt; }
  __syncthreads();
  float x=0,y=0,z=0,ww=0,ns=0,nc=0;
  for(int e=tid;e<NBLK_MAIN;e+=512){
    float4 p=partA[e]; x+=p.x; y+=p.y; z+=p.z; ww+=p.w;
    float2 q=part2[e]; ns+=q.x; nc+=q.y;
  }
  a0[tid]=x; a1[tid]=y; a2[tid]=z; a3[tid]=ww; s0[tid]=ns; s1[tid]=nc;
  __syncthreads();
  for(int o=256;o>0;o>>=1){
    if(tid<o){
      a0[tid]+=a0[tid+o]; a1[tid]+=a1[tid+o]; a2[tid]+=a2[tid+o]; a3[tid]+=a3[tid+o];
      s0[tid]+=s0[tid+o]; s1[tid]+=s1[tid+o];
    }
    __syncthreads();
  }
  if(tid==0){
    float negsum=s0[0], negcnt=s1[0];
    for(int im=0;im<NB;im++){ negsum+=tsumW[im]; negcnt+=tcntW[im]; }
    int np=acci[0];
    float npf=(float)np;
    float den2=fmaxf(2.f*npf,1.f);
    float lbox=a0[0]/den2+a1[0]/den2;
    float lcls=a2[0]/fmaxf(npf,1.f);
    float selc=npf+negcnt;
    float lobj=(a3[0]+negsum)/fmaxf(selc,1.f);
    out[0]=lbox+lcls+lobj;
    out[1]=lbox;
    out[2]=lobj;
    out[3]=lcls;
  }
}

extern "C" void kernel_launch(void* const* d_in, const int* in_sizes, int n_in,
                              void* d_out, int out_size, void* d_ws, size_t ws_size,
                              hipStream_t stream) {
  const float* f0=(const float*)d_in[0];
  const float* f1=(const float*)d_in[1];
  const float* f2=(const float*)d_in[2];
  const float* tg=(const float*)d_in[3];
  const float* priors=(const float*)d_in[4];
  int nt = in_sizes[3]/6;
  if(nt>NT_MAX) nt=NT_MAX;
  if(nt<1) nt=1;

  char* ws=(char*)d_ws;
  float*    ovr    =(float*)   (ws+O_OVR);
  int*      gix    =(int*)     (ws+O_GIX);
  float*    lsc    =(float*)   (ws+O_LSC);
  float*    bcearr =(float*)   (ws+O_BCE);
  int*      lj     =(int*)     (ws+O_LJ);
  unsigned long long* bpp=(unsigned long long*)(ws+O_BPP);
  unsigned* histP  =(unsigned*)(ws+O_HP);
  int*      histD  =(int*)     (ws+O_HD);
  float4*   partA  =(float4*)  (ws+O_PA);
  int*      partN  =(int*)     (ws+O_PN);
  float2*   part2  =(float2*)  (ws+O_P2);
  int*      binlist=(int*)     (ws+O_BINL);
  unsigned* histB  =(unsigned*)(ws+O_HB);
  int*      acci   =(int*)     (ws+O_ACCI);
  unsigned* zbase  =(unsigned*)(ws+O_HB);

  int ntb=(nt+255)/256;
  int b0=ZBLK+ntb, b1=b0+NBLK_MAIN;
  k_big0<<<b1+nt*NCHB,256,0,stream>>>(f0,f1,f2,tg,priors,nt,b0,b1,lj,zbase,ovr,gix,lsc,bcearr,histP,partN,bpp);
  k_bpsc<<<1,256,0,stream>>>(f0,f1,f2,tg,nt,bpp,lj,ovr,gix,lsc,bcearr,histD,acci);
  k_redscanA<<<NB,256,0,stream>>>(histP,histD,partN,acci);
  k_big2<<<2*NBLK_MAIN,256,0,stream>>>(f0,f1,f2,tg,priors,ovr,gix,lsc,bcearr,acci,nt,histB,partA);
  dim3 gm(GX_MAIN, NB);
  k_select<<<gm,256,0,stream>>>(lsc,bcearr,histB,acci,part2,binlist);
  k_tiesfinal<<<1,512,0,stream>>>(bcearr,histB,acci,binlist,partA,part2,(float*)d_out);
}

// Round 25
// 130.800 us; speedup vs baseline: 1.7948x; 1.1738x over previous
//
#include <hip/hip_runtime.h>
#include <math.h>

#define MTOT 42000
#define NB 8
#define NCLS 80
#define CAP_LIST 4096
#define NT_MAX 2048
#define GX_MAIN 165                 // ceil(42000/256)
#define NBLK_MAIN (GX_MAIN*NB)      // 1320
#define NCHB 8                      // bestprior chunks per target
#define CSB 5250                    // 42000/8
#define TCH 512                     // match target-staging chunk
#define TST 384                     // ties LDS staging per image

// ---- workspace byte offsets ----
#define O_OVR 0
#define O_GIX (O_OVR + NB*MTOT*4)
#define O_LSC (O_GIX + NB*MTOT*4)
#define O_BCE (O_LSC + NB*MTOT*4)
#define O_LJ  (O_BCE + NB*MTOT*4)
#define O_BPP (((O_LJ + NT_MAX*4 + 7)/8)*8)  // u64 partials [NT_MAX][NCHB]
#define O_HP  (O_BPP + NT_MAX*NCHB*8)    // coarse-hist partials [NBLK_MAIN][256]
#define O_HD  (O_HP + NBLK_MAIN*256*4)   // coarse-hist deltas [NB][256] int
#define O_PA  (O_HD + NB*256*4)          // posloss float4 partials [NBLK_MAIN]
#define O_PN  (O_PA + NBLK_MAIN*16)      // npos int partials [NBLK_MAIN]
#define O_P2  (O_PN + NBLK_MAIN*4)       // select float2 partials [NBLK_MAIN]
#define O_BINL (O_P2 + NBLK_MAIN*8)      // tie list [NB][CAP_LIST][2]
// kernel-zeroed region (zeroed by big0; consumed >=2 dispatches later):
#define O_HB  (((O_BINL + NB*CAP_LIST*2*4 + 255)/256)*256)
#define O_ACCI (O_HB + NB*256*4)         // acci[0..31]
#define O_ZEND (O_ACCI + 128)
#define ZWORDS ((O_ZEND - O_HB)/4)
#define ZBLK ((ZWORDS + 255)/256)
// acci: [0]=num_pos [2..9]=coarse ca [10..17]=kres [18..25]=tie counters [26]=npDelta

__device__ __forceinline__ float iou_cxcywh(float acx,float acy,float aw,float ah,
                                            float bcx,float bcy,float bw,float bh){
  float ax0=acx-aw*0.5f, ay0=acy-ah*0.5f, ax1=acx+aw*0.5f, ay1=acy+ah*0.5f;
  float bx0=bcx-bw*0.5f, by0=bcy-bh*0.5f, bx1=bcx+bw*0.5f, by1=bcy+bh*0.5f;
  float tlx=fmaxf(ax0,bx0), tly=fmaxf(ay0,by0);
  float brx=fminf(ax1,bx1), bry=fminf(ay1,by1);
  float wx=fmaxf(brx-tlx,0.f), wy=fmaxf(bry-tly,0.f);
  float inter=wx*wy;
  return inter/(aw*ah+bw*bh-inter+1e-9f);
}

__device__ __forceinline__ float sl1(float x){
  float ax=fabsf(x); return ax<1.f ? 0.5f*ax*ax : ax-0.5f;
}

__device__ __forceinline__ void feat_base(const float* f0,const float* f1,const float* f2,
                                          int i,int m,const float** basep,int* hwp){
  const float* fp; int hw, loc;
  if(m<32000){ fp=f0; hw=6400; loc=m; }
  else if(m<40000){ fp=f1; hw=1600; loc=m-32000; }
  else { fp=f2; hw=400; loc=m-40000; }
  int a=loc/hw, p=loc-a*hw;
  *basep = fp + (size_t)(i*425 + a*85)*(size_t)hw + p;
  *hwp = hw;
}

// inline fine-scan: 16-bit boundary bin + residual
__device__ __forceinline__ void fine_scan(const unsigned* hb,int ca,int kres,int* bs_out,int* r_out){
  if(ca==0x7fffffff){ *bs_out=0x7fffffff; *r_out=0; return; }
  int run=0, bs=-1, r=0;
  for(int f=255;f>=0;f--){
    int cb=(int)hb[f];
    if(run<kres && run+cb>=kres){ bs=(ca<<8)|f; r=kres-run; break; }
    run+=cb;
  }
  if(bs<0){ bs=(ca<<8); r=kres-run; }
  *bs_out=bs; *r_out=r;
}

// mega fusion: zero(HB/acci) | lj-prep | match(ballot-compact)+lc | bpA
__global__ void k_big0(const float* __restrict__ f0,const float* __restrict__ f1,const float* __restrict__ f2,
                       const float* __restrict__ tg,const float* __restrict__ priors,
                       int nt,int b0,int b1,
                       int* __restrict__ lj,unsigned* __restrict__ zbase,
                       float* __restrict__ ovr,int* __restrict__ gix,
                       float* __restrict__ lsc,float* __restrict__ bcearr,
                       unsigned* __restrict__ histP,int* __restrict__ partN,
                       unsigned long long* __restrict__ bpp){
  __shared__ float st[TCH*6];
  __shared__ float sc[TCH*4];
  __shared__ int cidx[TCH];
  __shared__ int s_ncomp;
  __shared__ unsigned long long su[256];
  __shared__ unsigned h[256];
  __shared__ int snp[4];
  int b=blockIdx.x, tid=threadIdx.x, lane=tid&63, wid=tid>>6;
  if(b<ZBLK){
    int w=b*256+tid;
    if(w<ZWORDS) zbase[w]=0u;
    return;
  }
  if(b<b0){
    int t=(b-ZBLK)*256+tid;
    if(t>=nt) return;
    int img=(int)tg[t*6];
    int j=0;
    for(int q=0;q<t;q++) if((int)tg[q*6]==img) j++;
    lj[t]=j;
    return;
  }
  if(b<b1){
    // ---- match + lc fused: stage chunk, wave-0 ballot-compact same-image targets
    // (t ascending => identical first-index tie-break), IoU over compact list ----
    int idx=b-b0;
    int i=idx/GX_MAIN, cb=idx-(idx/GX_MAIN)*GX_MAIN;
    int m=cb*256+tid;
    bool valid=(m<MTOT);
    h[tid]=0u;
    const float* basep=f0; int hw=6400;
    float obj=0.f;
    if(valid){ feat_base(f0,f1,f2,i,m,&basep,&hw); obj=basep[(size_t)4*hw]; }
    float4 pr=make_float4(0.f,0.f,1.f,1.f);
    if(valid) pr=((const float4*)priors)[m];
    float maxv=-1.f; int bi=0;
    for(int base=0;base<nt;base+=TCH){
      int nch=min(TCH,nt-base);
      for(int j=tid;j<nch;j+=256){
        #pragma unroll
        for(int q=0;q<6;q++) st[j*6+q]=tg[(base+j)*6+q];
      }
      __syncthreads();
      if(tid<64){
        int cnt=0;
        for(int bb=0;bb<nch;bb+=64){
          int j=bb+tid;
          bool f=(j<nch)&&((int)st[j*6]==i);
          unsigned long long mk=__ballot(f);
          if(f){
            int pos=cnt+__popcll(mk&((1ull<<tid)-1ull));
            cidx[pos]=base+j;
            sc[pos*4+0]=st[j*6+2]; sc[pos*4+1]=st[j*6+3];
            sc[pos*4+2]=st[j*6+4]; sc[pos*4+3]=st[j*6+5];
          }
          cnt+=__popcll(mk);
        }
        if(tid==0) s_ncomp=cnt;
      }
      __syncthreads();
      int nci=s_ncomp;
      if(valid){
        for(int j=0;j<nci;j++){
          float v=iou_cxcywh(sc[j*4+0],sc[j*4+1],sc[j*4+2],sc[j*4+3],pr.x,pr.y,pr.z,pr.w);
          if(v>maxv){ maxv=v; bi=cidx[j]; }
        }
      }
      __syncthreads();
    }
    int npos=0;
    if(valid){
      int gid=i*MTOT+m;
      ovr[gid]=maxv; gix[gid]=bi;
      int gi=min(max(bi,0),nt-1);
      float tc=tg[gi*6+1]+1.f;
      bool pos=(maxv>=0.5f)&&(tc>0.f);
      float sp=log1pf(expf(-fabsf(obj)));
      float bce=fmaxf(obj,0.f)-(pos?obj:0.f)+sp;
      float lc=pos?0.f:(fmaxf(-obj,0.f)+sp);
      lsc[gid]=lc; bcearr[gid]=bce;
      atomicAdd(&h[__float_as_uint(lc)>>24],1u);
      npos=pos?1:0;
    }
    #pragma unroll
    for(int o=32;o>0;o>>=1) npos+=__shfl_xor(npos,o);
    if(lane==0) snp[wid]=npos;
    __syncthreads();
    histP[(size_t)idx*256+tid]=h[tid];
    if(tid==0) partN[idx]=snp[0]+snp[1]+snp[2]+snp[3];
  } else {
    // ---- bpA: chunked best-prior partials (8 chunks/target) ----
    int idx=b-b1;
    int t=idx/NCHB, c=idx-(idx/NCHB)*NCHB;
    float acx=tg[t*6+2],acy=tg[t*6+3],aw=tg[t*6+4],ah=tg[t*6+5];
    int m0=c*CSB, m1=min(m0+CSB,MTOT);
    float bv=-1.f; int bm=0;
    for(int m=m0+tid;m<m1;m+=256){
      float4 pr=((const float4*)priors)[m];
      float v=iou_cxcywh(acx,acy,aw,ah,pr.x,pr.y,pr.z,pr.w);
      if(v>bv){ bv=v; bm=m; }
    }
    unsigned long long p=(bv<0.f)?0ull
        :(((unsigned long long)__float_as_uint(bv))<<32)|(unsigned)(~bm);
    su[tid]=p;
    __syncthreads();
    for(int o=128;o>0;o>>=1){
      if(tid<o){ if(su[tid+o]>su[tid]) su[tid]=su[tid+o]; }
      __syncthreads();
    }
    if(tid==0) bpp[(size_t)t*NCHB+c]=su[0];
  }
}

// bpB + forced-prior scatter + lc/bce/hist/np patch for survivors (single block)
__global__ void k_bpsc(const float* __restrict__ f0,const float* __restrict__ f1,const float* __restrict__ f2,
                       const float* __restrict__ tg,int nt,
                       const unsigned long long* __restrict__ bpp,
                       const int* __restrict__ lj,
                       float* __restrict__ ovr,const int* __restrict__ gix,
                       float* __restrict__ lsc,float* __restrict__ bcearr,
                       int* __restrict__ histD,int* __restrict__ acci){
  __shared__ int tbp[NT_MAX];
  __shared__ int timg[NT_MAX];
  __shared__ int hd[NB*256];
  __shared__ int npd;
  int tid=threadIdx.x;
  for(int e=tid;e<NB*256;e+=256) hd[e]=0;
  if(tid==0) npd=0;
  for(int t=tid;t<nt;t+=256){
    unsigned long long best=0ull;
    const unsigned long long* pp=&bpp[(size_t)t*NCHB];
    #pragma unroll
    for(int c=0;c<NCHB;c++){ unsigned long long v=pp[c]; if(v>best) best=v; }
    int bm=~((unsigned)(best&0xFFFFFFFFull));
    tbp[t]=min(max(bm,0),MTOT-1);
    timg[t]=(int)tg[t*6];
  }
  __syncthreads();
  for(int t=tid;t<nt;t+=256){
    int img=timg[t];
    if(img<0||img>=NB) continue;
    int myp=tbp[t];
    bool last=true;
    for(int q=t+1;q<nt;q++) if(timg[q]==img&&tbp[q]==myp){ last=false; break; }
    if(!last) continue;
    int gid=img*MTOT+myp;
    float ljv=(float)lj[t];
    float ov_old=ovr[gid];
    ovr[gid]=ljv;
    int gi=min(max(gix[gid],0),nt-1);
    float tc=tg[gi*6+1]+1.f;
    bool po=(ov_old>=0.5f)&&(tc>0.f);
    bool pn=(ljv>=0.5f)&&(tc>0.f);
    const float* basep; int hw;
    feat_base(f0,f1,f2,img,myp,&basep,&hw);
    float obj=basep[(size_t)4*hw];
    float sp=log1pf(expf(-fabsf(obj)));
    float bcen=fmaxf(obj,0.f)-(pn?obj:0.f)+sp;
    float lcn=pn?0.f:(fmaxf(-obj,0.f)+sp);
    float lco=lsc[gid];
    lsc[gid]=lcn; bcearr[gid]=bcen;
    atomicAdd(&hd[img*256+(int)(__float_as_uint(lco)>>24)],-1);
    atomicAdd(&hd[img*256+(int)(__float_as_uint(lcn)>>24)], 1);
    atomicAdd(&npd,(pn?1:0)-(po?1:0));
  }
  __syncthreads();
  for(int e=tid;e<NB*256;e+=256) histD[e]=hd[e];
  if(tid==0) acci[26]=npd;
}

// horizontal fusion: [0,1320) redundant np+coarse-scan + fine hist | [1320,2640) positive losses
__global__ void k_big2(const float* __restrict__ f0,const float* __restrict__ f1,const float* __restrict__ f2,
                       const float* __restrict__ tg,const float* __restrict__ priors,
                       const float* __restrict__ ovr,const int* __restrict__ gix,
                       const float* __restrict__ lsc,const float* __restrict__ bcearr,
                       const int* __restrict__ partN,const unsigned* __restrict__ histP,
                       const int* __restrict__ histD,int* __restrict__ acci,int nt,
                       unsigned* __restrict__ histB,float4* __restrict__ partA){
  __shared__ int an[256];
  __shared__ int hc[256];
  __shared__ unsigned hf[256];
  __shared__ int s_ca;
  __shared__ float rA[4],rB[4],rC[4],rD[4];
  int b=blockIdx.x, tid=threadIdx.x, lane=tid&63, wid=tid>>6;
  if(b<NBLK_MAIN){
    int i=b/GX_MAIN, cb=b-(b/GX_MAIN)*GX_MAIN;
    int n=0;
    for(int e=tid;e<NBLK_MAIN;e+=256) n+=partN[e];
    an[tid]=n;
    __syncthreads();
    for(int o=128;o>0;o>>=1){ if(tid<o) an[tid]+=an[tid+o]; __syncthreads(); }
    int np=an[0]+acci[26];
    int cbn=histD[i*256+tid];
    for(int blk=0;blk<GX_MAIN;blk++) cbn+=(int)histP[(size_t)(i*GX_MAIN+blk)*256+tid];
    hc[tid]=cbn;
    __syncthreads();
    if(tid==0){
      int kk=min(np,MTOT-np);
      int ca,kres;
      if(kk<=0){ ca=0x7fffffff; kres=0; }
      else{
        int run=0; ca=-1; kres=0;
        for(int c2=255;c2>=0;c2--){
          int x=hc[c2];
          if(run<kk&&run+x>=kk){ ca=c2; kres=kk-run; break; }
          run+=x;
        }
        if(ca<0){ ca=0; kres=kk-run; }
      }
      s_ca=ca;
      if(cb==0){ acci[2+i]=ca; acci[10+i]=kres; if(i==0) acci[0]=np; }
    }
    hf[tid]=0u;
    __syncthreads();
    int ca=s_ca;
    int m=cb*256+tid;
    if(m<MTOT && ca!=0x7fffffff){
      unsigned u=__float_as_uint(lsc[i*MTOT+m]);
      if((int)(u>>24)==ca) atomicAdd(&hf[(u>>16)&0xFF],1u);
    }
    __syncthreads();
    unsigned c=hf[tid];
    if(c) atomicAdd(&histB[i*256+tid],c);
  } else {
    int idx=b-NBLK_MAIN;
    int i=idx/GX_MAIN, cb=idx-(idx/GX_MAIN)*GX_MAIN;
    int m=cb*256+tid;
    bool valid=(m<MTOT);
    float lxy=0.f,lwh=0.f,bcep=0.f,wce=0.f;
    bool pos=false; int gi=0;
    if(valid){
      int gid=i*MTOT+m;
      float ov=ovr[gid];
      gi=min(max(gix[gid],0),nt-1);
      float tc=tg[gi*6+1]+1.f;
      pos=(ov>=0.5f)&&(tc>0.f);
      if(pos){
        const float* base; int hw;
        feat_base(f0,f1,f2,i,m,&base,&hw);
        bcep=bcearr[gid];
        float4 pr=((const float4*)priors)[m];
        float bx=tg[gi*6+2],by=tg[gi*6+3],bw=tg[gi*6+4],bh=tg[gi*6+5];
        float tx=(bx-pr.x)/pr.z, ty=(by-pr.y)/pr.w;
        float tw=logf(bw/pr.z), th=logf(bh/pr.w);
        lxy=sl1(base[0]-tx)+sl1(base[(size_t)hw]-ty);
        lwh=sl1(base[(size_t)2*hw]-tw)+sl1(base[(size_t)3*hw]-th);
      }
    }
    unsigned long long mask=__ballot(valid&&pos);
    while(mask){
      int s=__ffsll(mask)-1;
      mask&=mask-1;
      int m_s=__shfl(m,s);
      int gi_s=__shfl(gi,s);
      const float* bs2; int hws;
      feat_base(f0,f1,f2,i,m_s,&bs2,&hws);
      int label=(int)(tg[gi_s*6+1]+1.f)-1;
      label=min(NCLS-1,max(0,label));
      float v0=bs2[(size_t)(5+lane)*hws];
      float v1=(lane<16)?bs2[(size_t)(69+lane)*hws]:-3.0e38f;
      float mx=fmaxf(v0,v1);
      #pragma unroll
      for(int o=32;o>0;o>>=1) mx=fmaxf(mx,__shfl_xor(mx,o));
      float se=expf(v0-mx)+((lane<16)?expf(v1-mx):0.f);
      float xl=((lane==label)?v0:0.f)+((lane<16&&lane+64==label)?v1:0.f);
      #pragma unroll
      for(int o=32;o>0;o>>=1){ se+=__shfl_xor(se,o); xl+=__shfl_xor(xl,o); }
      wce+=logf(se)+mx-xl;
    }
    #pragma unroll
    for(int o=32;o>0;o>>=1){
      lxy+=__shfl_xor(lxy,o); lwh+=__shfl_xor(lwh,o); bcep+=__shfl_xor(bcep,o);
    }
    if(lane==0){ rA[wid]=lxy; rB[wid]=lwh; rC[wid]=wce; rD[wid]=bcep; }
    __syncthreads();
    if(tid==0)
      partA[idx]=make_float4(rA[0]+rA[1]+rA[2]+rA[3], rB[0]+rB[1]+rB[2]+rB[3],
                             rC[0]+rC[1]+rC[2]+rC[3], rD[0]+rD[1]+rD[2]+rD[3]);
  }
}

// select negatives above 16-bit threshold (fine_scan locally); partials + tie list
__global__ void k_select(const float* __restrict__ lsc,const float* __restrict__ bcearr,
                         const unsigned* __restrict__ histB,
                         int* __restrict__ acci,float2* __restrict__ part2,
                         int* __restrict__ binlist){
  __shared__ unsigned hb[256];
  __shared__ int sbs;
  __shared__ float ss[4]; __shared__ float sc2[4];
  int tid=threadIdx.x, lane=tid&63, wid=tid>>6;
  int i=blockIdx.y;
  int ca=acci[2+i], kres=acci[10+i];
  hb[tid]=(ca==0x7fffffff)?0u:histB[i*256+tid];
  __syncthreads();
  if(tid==0){ int bs,r; fine_scan(hb,ca,kres,&bs,&r); sbs=bs; }
  __syncthreads();
  int bs_=sbs;
  int m=blockIdx.x*256+tid;
  float s=0.f, c=0.f;
  if(m<MTOT){
    int gid=i*MTOT+m;
    unsigned u=__float_as_uint(lsc[gid]);
    int bin=(int)(u>>16);
    if(bin>bs_){ s=bcearr[gid]; c=1.f; }
    else if(bin==bs_){
      int idx=atomicAdd(&acci[18+i],1);
      if(idx<CAP_LIST){
        binlist[((size_t)i*CAP_LIST+idx)*2  ]=(int)u;
        binlist[((size_t)i*CAP_LIST+idx)*2+1]=gid;
      }
    }
  }
  #pragma unroll
  for(int o=32;o>0;o>>=1){ s+=__shfl_xor(s,o); c+=__shfl_xor(c,o); }
  if(lane==0){ ss[wid]=s; sc2[wid]=c; }
  __syncthreads();
  if(tid==0) part2[blockIdx.y*gridDim.x+blockIdx.x]=make_float2(ss[0]+ss[1]+ss[2]+ss[3], sc2[0]+sc2[1]+sc2[2]+sc2[3]);
}

// ties (wave w = image w, parallel latency chains) + final combine; 1 block x 512
__global__ void k_tiesfinal(const float* __restrict__ bcearr,const unsigned* __restrict__ histB,
                            int* __restrict__ acci,const int* __restrict__ binlist,
                            const float4* __restrict__ partA,const float2* __restrict__ part2,
                            float* __restrict__ out){
  __shared__ unsigned hb[NB*256];
  __shared__ int sbs[NB], sr2[NB];
  __shared__ int stg[NB*TST*2];
  __shared__ float tsumW[NB]; __shared__ float tcntW[NB];
  __shared__ float a0[512],a1[512],a2[512],a3[512],s0[512],s1[512];
  int tid=threadIdx.x, w=tid>>6, lane=tid&63;
  int ca=acci[2+w], kres=acci[10+w];
  for(int e=lane;e<256;e+=64) hb[w*256+e]=(ca==0x7fffffff)?0u:histB[w*256+e];
  __syncthreads();
  if(lane==0){ int bs,r; fine_scan(&hb[w*256],ca,kres,&bs,&r); sbs[w]=bs; sr2[w]=r; }
  __syncthreads();
  int bs=sbs[w], r=sr2[w];
  int n=min(acci[18+w],CAP_LIST);
  int nst=min(n,TST);
  if(bs!=0x7fffffff){
    for(int e=lane;e<nst;e+=64){
      stg[(w*TST+e)*2  ]=binlist[((size_t)w*CAP_LIST+e)*2  ];
      stg[(w*TST+e)*2+1]=binlist[((size_t)w*CAP_LIST+e)*2+1];
    }
  }
  __syncthreads();
  float tsum=0.f, tcnt=0.f;
  if(bs!=0x7fffffff){
    for(int e=lane;e<n;e+=64){
      unsigned ue; int ge;
      if(e<nst){ ue=(unsigned)stg[(w*TST+e)*2]; ge=stg[(w*TST+e)*2+1]; }
      else{ ue=(unsigned)binlist[((size_t)w*CAP_LIST+e)*2]; ge=binlist[((size_t)w*CAP_LIST+e)*2+1]; }
      int rank=0;
      for(int q=0;q<n;q++){
        unsigned uq; int gq;
        if(q<nst){ uq=(unsigned)stg[(w*TST+q)*2]; gq=stg[(w*TST+q)*2+1]; }
        else{ uq=(unsigned)binlist[((size_t)w*CAP_LIST+q)*2]; gq=binlist[((size_t)w*CAP_LIST+q)*2+1]; }
        rank += ((uq>ue)||(uq==ue&&gq<ge))?1:0;
      }
      if(rank<r){ tsum+=bcearr[ge]; tcnt+=1.f; }
    }
  }
  #pragma unroll
  for(int o=32;o>0;o>>=1){ tsum+=__shfl_xor(tsum,o); tcnt+=__shfl_xor(tcnt,o); }
  if(lane==0){ tsumW[w]=tsum; tcntW[w]=tcnt; }
  __syncthreads();
  float x=0,y=0,z=0,ww=0,ns=0,nc=0;
  for(int e=tid;e<NBLK_MAIN;e+=512){
    float4 p=partA[e]; x+=p.x; y+=p.y; z+=p.z; ww+=p.w;
    float2 q=part2[e]; ns+=q.x; nc+=q.y;
  }
  a0[tid]=x; a1[tid]=y; a2[tid]=z; a3[tid]=ww; s0[tid]=ns; s1[tid]=nc;
  __syncthreads();
  for(int o=256;o>0;o>>=1){
    if(tid<o){
      a0[tid]+=a0[tid+o]; a1[tid]+=a1[tid+o]; a2[tid]+=a2[tid+o]; a3[tid]+=a3[tid+o];
      s0[tid]+=s0[tid+o]; s1[tid]+=s1[tid+o];
    }
    __syncthreads();
  }
  if(tid==0){
    float negsum=s0[0], negcnt=s1[0];
    for(int im=0;im<NB;im++){ negsum+=tsumW[im]; negcnt+=tcntW[im]; }
    int np=acci[0];
    float npf=(float)np;
    float den2=fmaxf(2.f*npf,1.f);
    float lbox=a0[0]/den2+a1[0]/den2;
    float lcls=a2[0]/fmaxf(npf,1.f);
    float selc=npf+negcnt;
    float lobj=(a3[0]+negsum)/fmaxf(selc,1.f);
    out[0]=lbox+lcls+lobj;
    out[1]=lbox;
    out[2]=lobj;
    out[3]=lcls;
  }
}

extern "C" void kernel_launch(void* const* d_in, const int* in_sizes, int n_in,
                              void* d_out, int out_size, void* d_ws, size_t ws_size,
                              hipStream_t stream) {
  const float* f0=(const float*)d_in[0];
  const float* f1=(const float*)d_in[1];
  const float* f2=(const float*)d_in[2];
  const float* tg=(const float*)d_in[3];
  const float* priors=(const float*)d_in[4];
  int nt = in_sizes[3]/6;
  if(nt>NT_MAX) nt=NT_MAX;
  if(nt<1) nt=1;

  char* ws=(char*)d_ws;
  float*    ovr    =(float*)   (ws+O_OVR);
  int*      gix    =(int*)     (ws+O_GIX);
  float*    lsc    =(float*)   (ws+O_LSC);
  float*    bcearr =(float*)   (ws+O_BCE);
  int*      lj     =(int*)     (ws+O_LJ);
  unsigned long long* bpp=(unsigned long long*)(ws+O_BPP);
  unsigned* histP  =(unsigned*)(ws+O_HP);
  int*      histD  =(int*)     (ws+O_HD);
  float4*   partA  =(float4*)  (ws+O_PA);
  int*      partN  =(int*)     (ws+O_PN);
  float2*   part2  =(float2*)  (ws+O_P2);
  int*      binlist=(int*)     (ws+O_BINL);
  unsigned* histB  =(unsigned*)(ws+O_HB);
  int*      acci   =(int*)     (ws+O_ACCI);
  unsigned* zbase  =(unsigned*)(ws+O_HB);

  int ntb=(nt+255)/256;
  int b0=ZBLK+ntb, b1=b0+NBLK_MAIN;
  k_big0<<<b1+nt*NCHB,256,0,stream>>>(f0,f1,f2,tg,priors,nt,b0,b1,lj,zbase,ovr,gix,lsc,bcearr,histP,partN,bpp);
  k_bpsc<<<1,256,0,stream>>>(f0,f1,f2,tg,nt,bpp,lj,ovr,gix,lsc,bcearr,histD,acci);
  k_big2<<<2*NBLK_MAIN,256,0,stream>>>(f0,f1,f2,tg,priors,ovr,gix,lsc,bcearr,partN,histP,histD,acci,nt,histB,partA);
  dim3 gm(GX_MAIN, NB);
  k_select<<<gm,256,0,stream>>>(lsc,bcearr,histB,acci,part2,binlist);
  k_tiesfinal<<<1,512,0,stream>>>(bcearr,histB,acci,binlist,partA,part2,(float*)d_out);
}